// Round 12
// baseline (516.156 us; speedup 1.0000x reference)
//
#include <hip/hip_runtime.h>

#define N_NODES 50000
#define N_EDGES 800000
#define N_GRAPHS 512
#define IN_C 128
#define HID 256
#define OUT_C 16

typedef __attribute__((ext_vector_type(8))) short short8;
typedef __attribute__((ext_vector_type(4))) float f32x4;

__device__ __forceinline__ float bf2f(unsigned short u) {
    return __uint_as_float(((unsigned int)u) << 16);
}
__device__ __forceinline__ unsigned short f2bf(float f) {
    unsigned int u = __float_as_uint(f);
    u += 0x7fff + ((u >> 16) & 1);   // RNE
    return (unsigned short)(u >> 16);
}

// ===========================================================================
// Prep (single dispatch): x -> bf16, six weight transposes (K x 256 fp32 ->
// 256 x K bf16), zero deg, zero sums.
// ===========================================================================
struct PrepArgs {
    const float* x;
    const float* w[6];      // K x 256 row-major; K = 128 for w[0], else 256
    ushort* xbf;
    ushort* wt[6];
    int* deg;
    float* sums;
};

__global__ __launch_bounds__(256) void prep_kernel(PrepArgs a) {
    const int X4    = N_NODES * IN_C / 4;
    const int TW    = IN_C * HID;
    const int TH    = HID * HID;
    const int TBASE = X4;
    const int TEND  = TBASE + TW + 5 * TH;
    const int D4    = N_NODES / 4;
    const int DBASE = TEND;
    const int SBASE = DBASE + D4;
    const int S4    = N_GRAPHS * HID / 4;
    const long total = (long)SBASE + S4;

    long stride = (long)gridDim.x * blockDim.x;
    for (long i = (long)blockIdx.x * blockDim.x + threadIdx.x; i < total; i += stride) {
        if (i < X4) {
            float4 v = ((const float4*)a.x)[i];
            ushort4 o;
            o.x = f2bf(v.x); o.y = f2bf(v.y); o.z = f2bf(v.z); o.w = f2bf(v.w);
            ((ushort4*)a.xbf)[i] = o;
        } else if (i < TEND) {
            long r = i - TBASE;
            int wi, shift;
            long off;
            if (r < TW) { wi = 0; shift = 7; off = r; }
            else { r -= TW; wi = 1 + (int)(r / TH); shift = 8; off = r % TH; }
            int n = (int)(off >> shift);
            int k = (int)(off - ((long)n << shift));
            a.wt[wi][off] = f2bf(a.w[wi][(long)k * HID + n]);
        } else if (i < SBASE) {
            ((int4*)a.deg)[i - DBASE] = make_int4(0, 0, 0, 0);
        } else {
            ((float4*)a.sums)[i - SBASE] = make_float4(0.f, 0.f, 0.f, 0.f);
        }
    }
}

// ===========================================================================
// CSR build: deg histogram -> scan (2 fused dispatches) -> bucket by dst.
// ===========================================================================
__global__ void deg_kernel(const int* __restrict__ dst, int* __restrict__ deg) {
    int e = blockIdx.x * blockDim.x + threadIdx.x;
    if (e < N_EDGES) atomicAdd(&deg[dst[e]], 1);
}

__global__ __launch_bounds__(256) void scan_block(const int* __restrict__ deg,
                                                  int* __restrict__ partial,
                                                  int* __restrict__ blockSums) {
    __shared__ int s[256];
    int t = threadIdx.x;
    int i = blockIdx.x * 256 + t;
    int v = (i < N_NODES) ? deg[i] : 0;
    s[t] = v;
    __syncthreads();
    #pragma unroll
    for (int off = 1; off < 256; off <<= 1) {
        int add = (t >= off) ? s[t - off] : 0;
        __syncthreads();
        s[t] += add;
        __syncthreads();
    }
    if (i < N_NODES) partial[i] = s[t] - v;
    if (t == 255) blockSums[blockIdx.x] = s[255];
}

__global__ __launch_bounds__(256) void add_offsets_fused(
    const int* __restrict__ partial, const int* __restrict__ blockSums,
    int* __restrict__ rowptr, int* __restrict__ cursor, int nb) {
    __shared__ int s[256];
    __shared__ int myOff;
    int t = threadIdx.x;
    int v = (t < nb) ? blockSums[t] : 0;
    s[t] = v;
    __syncthreads();
    #pragma unroll
    for (int off = 1; off < 256; off <<= 1) {
        int add = (t >= off) ? s[t - off] : 0;
        __syncthreads();
        s[t] += add;
        __syncthreads();
    }
    if (t == blockIdx.x) myOff = s[t] - v;
    __syncthreads();
    int i = blockIdx.x * 256 + t;
    if (i < N_NODES) {
        int r = partial[i] + myOff;
        rowptr[i] = r;
        cursor[i] = r;
    }
    if (i == 0) rowptr[N_NODES] = N_EDGES;
}

__global__ void bucket_edges(const int* __restrict__ src, const int* __restrict__ dst,
                             int* __restrict__ cursor, int* __restrict__ srcSorted) {
    int e = blockIdx.x * blockDim.x + threadIdx.x;
    if (e >= N_EDGES) return;
    int p = atomicAdd(&cursor[dst[e]], 1);
    srcSorted[p] = src[e];
}

// ===========================================================================
// Aggregation (best measured config, VGPR 28): out[n] = h[n] + sum h[src].
// ===========================================================================
template <int C>
__global__ __launch_bounds__(256) void gin_aggregate_bf(const ushort* __restrict__ h,
                                                        const int* __restrict__ rowptr,
                                                        const int* __restrict__ srcIdx,
                                                        ushort* __restrict__ out) {
    constexpr int LPN = C / 8;
    constexpr int NPW = 64 / LPN;
    int wave = threadIdx.x >> 6;
    int lane = threadIdx.x & 63;
    int node = blockIdx.x * 4 + wave;
    if (node >= N_NODES) return;
    int sub = lane / LPN;
    int l = lane & (LPN - 1);
    int coff = l * 8;

    float acc[8];
    #pragma unroll
    for (int v = 0; v < 8; ++v) acc[v] = 0.f;

    if (sub == 0) {
        short8 sv = *(const short8*)(h + (long)node * C + coff);
        #pragma unroll
        for (int v = 0; v < 8; ++v) acc[v] += bf2f((unsigned short)sv[v]);
    }

    int beg = rowptr[node], end = rowptr[node + 1];
    int k = beg;
    for (; k + 4 * NPW <= end; k += 4 * NPW) {
        int si[4];
        #pragma unroll
        for (int u = 0; u < 4; ++u) si[u] = srcIdx[k + u * NPW + sub];
        short8 r[4];
        #pragma unroll
        for (int u = 0; u < 4; ++u) r[u] = *(const short8*)(h + (long)si[u] * C + coff);
        #pragma unroll
        for (int u = 0; u < 4; ++u)
            #pragma unroll
            for (int v = 0; v < 8; ++v) acc[v] += bf2f((unsigned short)r[u][v]);
    }
    for (; k < end; k += NPW) {
        int idx = k + sub;
        if (idx < end) {
            int sidx = srcIdx[idx];
            short8 r = *(const short8*)(h + (long)sidx * C + coff);
            #pragma unroll
            for (int v = 0; v < 8; ++v) acc[v] += bf2f((unsigned short)r[v]);
        }
    }

    #pragma unroll
    for (int v = 0; v < 8; ++v) {
        if constexpr (NPW == 4) acc[v] += __shfl_xor(acc[v], 16);
        acc[v] += __shfl_xor(acc[v], 32);
    }

    if (sub == 0) {
        short8 o;
        #pragma unroll
        for (int v = 0; v < 8; ++v) o[v] = (short)f2bf(acc[v]);
        *(short8*)(out + (long)node * C + coff) = o;
    }
}

// ===========================================================================
// Fused 2-layer MLP: out = relu(relu(A@W1+b1)@W2+b2), bf16 in/out.
// __launch_bounds__(256, 4): 4 blocks/CU (16 waves/CU), LDS 32 KB.
// Output path (non-pool): phase-C result -> Ls (swizzled, 2-way-free banks)
// -> cooperative contiguous short8 stores (2K vector stores vs 16K scalar).
// FUSE_POOL: epilogue accumulates into graph sums (atomics), no store.
// All address offsets are 32-bit (max offset < 2^31).
// ===========================================================================
template <int K1, bool FUSE_POOL>
__global__ __launch_bounds__(256, 4) void gin_mlp(
    const ushort* __restrict__ A,
    const ushort* __restrict__ w1t,
    const float* __restrict__ b1,
    const ushort* __restrict__ w2t,
    const float* __restrict__ b2,
    ushort* __restrict__ out,
    const int* __restrict__ batch,
    float* __restrict__ sums,
    int M)
{
    __shared__ short Ls[2048 * 8];      // 32 KB

    constexpr int NCH1 = K1 / 8;
    constexpr int NSLOT1 = 64 * NCH1;

    int t = threadIdx.x;
    int lane = t & 63;
    int wv = t >> 6;
    int quad = lane >> 4;
    int l15 = lane & 15;
    int swz = l15 & 7;
    int row0 = blockIdx.x * 64;
    int col0 = wv * 64;

    #pragma unroll
    for (int c = 0; c < NSLOT1; c += 256) {
        int s = c + t;
        int row = s / NCH1;
        int kcs = s & (NCH1 - 1);
        int kc = kcs ^ (row & 7);
        int grow = row0 + row;
        if (grow >= M) grow = M - 1;
        short8 v = *(const short8*)(A + (unsigned)grow * K1 + kc * 8);
        *(short8*)&Ls[s * 8] = v;
    }
    __syncthreads();

    const f32x4 zero = {0.f, 0.f, 0.f, 0.f};
    f32x4 acc[4][4];

    #pragma unroll
    for (int i = 0; i < 4; ++i)
        #pragma unroll
        for (int j = 0; j < 4; ++j) acc[i][j] = zero;

    int brow[4];
    #pragma unroll
    for (int j = 0; j < 4; ++j)
        brow[j] = (col0 + j * 16 + l15) * K1;

    #pragma unroll
    for (int s = 0; s < K1 / 32; ++s) {
        short8 a[4], b[4];
        #pragma unroll
        for (int i = 0; i < 4; ++i) {
            int row = i * 16 + l15;
            int slot = row * NCH1 + ((s * 4 + quad) ^ swz);
            a[i] = *(const short8*)&Ls[slot * 8];
        }
        #pragma unroll
        for (int j = 0; j < 4; ++j)
            b[j] = *(const short8*)(w1t + brow[j] + s * 32 + quad * 8);
        #pragma unroll
        for (int i = 0; i < 4; ++i)
            #pragma unroll
            for (int j = 0; j < 4; ++j)
                acc[i][j] = __builtin_amdgcn_mfma_f32_16x16x32_bf16(a[i], b[j], acc[i][j], 0, 0, 0);
    }
    __syncthreads();

    {
        float bv[4];
        #pragma unroll
        for (int j = 0; j < 4; ++j) bv[j] = b1[col0 + j * 16 + l15];
        #pragma unroll
        for (int i = 0; i < 4; ++i)
            #pragma unroll
            for (int j = 0; j < 4; ++j) {
                int col = col0 + j * 16 + l15;
                int kc2 = col >> 3, sub = col & 7;
                #pragma unroll
                for (int r = 0; r < 4; ++r) {
                    int row = i * 16 + quad * 4 + r;
                    int slot = row * 32 + (kc2 ^ (row & 7));
                    float o = fmaxf(acc[i][j][r] + bv[j], 0.f);
                    Ls[slot * 8 + sub] = (short)f2bf(o);
                }
            }
    }
    __syncthreads();

    #pragma unroll
    for (int i = 0; i < 4; ++i)
        #pragma unroll
        for (int j = 0; j < 4; ++j) acc[i][j] = zero;

    int brow2[4];
    #pragma unroll
    for (int j = 0; j < 4; ++j)
        brow2[j] = (col0 + j * 16 + l15) * 256;

    #pragma unroll
    for (int s = 0; s < 8; ++s) {
        short8 a[4], b[4];
        #pragma unroll
        for (int i = 0; i < 4; ++i) {
            int row = i * 16 + l15;
            int slot = row * 32 + ((s * 4 + quad) ^ swz);
            a[i] = *(const short8*)&Ls[slot * 8];
        }
        #pragma unroll
        for (int j = 0; j < 4; ++j)
            b[j] = *(const short8*)(w2t + brow2[j] + s * 32 + quad * 8);
        #pragma unroll
        for (int i = 0; i < 4; ++i)
            #pragma unroll
            for (int j = 0; j < 4; ++j)
                acc[i][j] = __builtin_amdgcn_mfma_f32_16x16x32_bf16(a[i], b[j], acc[i][j], 0, 0, 0);
    }

    float bv[4];
    #pragma unroll
    for (int j = 0; j < 4; ++j) bv[j] = b2[col0 + j * 16 + l15];

    if constexpr (!FUSE_POOL) {
        // Bias+relu result -> Ls (swizzled), then coalesced short8 stores.
        __syncthreads();   // all Ls (h1) reads complete before overwrite
        #pragma unroll
        for (int i = 0; i < 4; ++i)
            #pragma unroll
            for (int j = 0; j < 4; ++j) {
                int col = col0 + j * 16 + l15;
                int kc2 = col >> 3, sub = col & 7;
                #pragma unroll
                for (int r = 0; r < 4; ++r) {
                    int row = i * 16 + quad * 4 + r;
                    int slot = row * 32 + (kc2 ^ (row & 7));
                    float o = fmaxf(acc[i][j][r] + bv[j], 0.f);
                    Ls[slot * 8 + sub] = (short)f2bf(o);
                }
            }
        __syncthreads();
        #pragma unroll
        for (int c = 0; c < 2048; c += 256) {
            int s2 = c + t;
            int row = s2 >> 5;
            int kcs = s2 & 31;
            int grow = row0 + row;
            if (grow < M) {
                short8 v = *(const short8*)&Ls[(row * 32 + (kcs ^ (row & 7))) * 8];
                *(short8*)(out + (unsigned)grow * 256 + kcs * 8) = v;
            }
        }
    } else {
        float pacc[4];
        #pragma unroll
        for (int j = 0; j < 4; ++j) pacc[j] = 0.f;
        int cur = -1;
        #pragma unroll
        for (int i = 0; i < 4; ++i) {
            #pragma unroll
            for (int r = 0; r < 4; ++r) {
                int row = row0 + i * 16 + quad * 4 + r;
                if (row >= M) continue;
                int g = batch[row];
                if (g != cur) {
                    if (cur >= 0) {
                        #pragma unroll
                        for (int j = 0; j < 4; ++j)
                            atomicAdd(&sums[(unsigned)cur * 256 + col0 + j * 16 + l15], pacc[j]);
                    }
                    cur = g;
                    #pragma unroll
                    for (int j = 0; j < 4; ++j) pacc[j] = 0.f;
                }
                #pragma unroll
                for (int j = 0; j < 4; ++j)
                    pacc[j] += fmaxf(acc[i][j][r] + bv[j], 0.f);
            }
        }
        if (cur >= 0) {
            #pragma unroll
            for (int j = 0; j < 4; ++j)
                atomicAdd(&sums[(unsigned)cur * 256 + col0 + j * 16 + l15], pacc[j]);
        }
    }
}

// ===========================================================================
// Head MLP (fp32): one block per graph; count via binary search on batch.
// ===========================================================================
__global__ __launch_bounds__(256) void final_mlp_kernel(
    const float* __restrict__ sums, const int* __restrict__ batch,
    const float* __restrict__ w1, const float* __restrict__ b1,
    const float* __restrict__ w2, const float* __restrict__ b2,
    float* __restrict__ out) {
    __shared__ float row[HID];
    __shared__ float hid[HID];
    __shared__ int cntS;
    int g = blockIdx.x;
    int t = threadIdx.x;
    if (t == 0) {
        int lo = 0, hi = N_NODES;
        while (lo < hi) { int m = (lo + hi) >> 1; if (batch[m] < g) lo = m + 1; else hi = m; }
        int lo2 = lo, hi2 = N_NODES;
        while (lo2 < hi2) { int m = (lo2 + hi2) >> 1; if (batch[m] < g + 1) lo2 = m + 1; else hi2 = m; }
        cntS = lo2 - lo;
    }
    __syncthreads();
    float cnt = fmaxf((float)cntS, 1.0f);
    row[t] = sums[(long)g * HID + t] / cnt;
    __syncthreads();
    float acc = b1[t];
    for (int k = 0; k < HID; ++k) acc += row[k] * w1[k * HID + t];
    hid[t] = fmaxf(acc, 0.f);
    __syncthreads();
    if (t < OUT_C) {
        float o = b2[t];
        for (int k = 0; k < HID; ++k) o += hid[k] * w2[k * OUT_C + t];
        out[(long)g * OUT_C + t] = o;
    }
}

// ---------------------------------------------------------------------------
extern "C" void kernel_launch(void* const* d_in, const int* in_sizes, int n_in,
                              void* d_out, int out_size, void* d_ws, size_t ws_size,
                              hipStream_t stream) {
    const float* x     = (const float*)d_in[0];
    const int*   ei    = (const int*)d_in[1];
    const int*   batch = (const int*)d_in[2];
    const int*   src   = ei;
    const int*   dst   = ei + N_EDGES;

    const float* c_w1[3] = { (const float*)d_in[3],  (const float*)d_in[7],  (const float*)d_in[11] };
    const float* c_b1[3] = { (const float*)d_in[4],  (const float*)d_in[8],  (const float*)d_in[12] };
    const float* c_w2[3] = { (const float*)d_in[5],  (const float*)d_in[9],  (const float*)d_in[13] };
    const float* c_b2[3] = { (const float*)d_in[6],  (const float*)d_in[10], (const float*)d_in[14] };
    const float* out_w1 = (const float*)d_in[15];
    const float* out_b1 = (const float*)d_in[16];
    const float* out_w2 = (const float*)d_in[17];
    const float* out_b2 = (const float*)d_in[18];

    // ---- Workspace layout (16B aligned) ----
    char* p = (char*)d_ws;
    auto alloc = [&](size_t bytes) {
        char* r = p;
        p += (bytes + 15) & ~(size_t)15;
        return r;
    };
    ushort* xbf  = (ushort*)alloc((size_t)N_NODES * IN_C * 2);
    ushort* bufA = (ushort*)alloc((size_t)N_NODES * HID * 2);
    ushort* bufB = (ushort*)alloc((size_t)N_NODES * HID * 2);
    ushort* wt[6];
    wt[0] = (ushort*)alloc((size_t)IN_C * HID * 2);
    for (int i = 1; i < 6; ++i) wt[i] = (ushort*)alloc((size_t)HID * HID * 2);
    float* sums   = (float*)alloc((size_t)N_GRAPHS * HID * 4);
    int* deg       = (int*)alloc((size_t)N_NODES * 4);
    int* rowptr    = (int*)alloc((size_t)(N_NODES + 1) * 4);
    int* blockSums = (int*)alloc(256 * 4);
    int* cursor    = (int*)alloc((size_t)N_NODES * 4);
    int* srcSorted = (int*)alloc((size_t)N_EDGES * 4);

    const int nb = (N_NODES + 255) / 256;

    // ---- Prep: one dispatch for casts + transposes + zeroing ----
    {
        PrepArgs a;
        a.x = x;
        a.w[0] = c_w1[0]; a.w[1] = c_w2[0];
        a.w[2] = c_w1[1]; a.w[3] = c_w2[1];
        a.w[4] = c_w1[2]; a.w[5] = c_w2[2];
        a.xbf = xbf;
        for (int i = 0; i < 6; ++i) a.wt[i] = wt[i];
        a.deg = deg;
        a.sums = sums;
        prep_kernel<<<2048, 256, 0, stream>>>(a);
    }

    // ---- Build CSR by dst ----
    deg_kernel<<<(N_EDGES + 255) / 256, 256, 0, stream>>>(dst, deg);
    scan_block<<<nb, 256, 0, stream>>>(deg, rowptr, blockSums);
    add_offsets_fused<<<nb, 256, 0, stream>>>(rowptr, blockSums, rowptr, cursor, nb);
    bucket_edges<<<(N_EDGES + 255) / 256, 256, 0, stream>>>(src, dst, cursor, srcSorted);

    const int aggGrid = (N_NODES + 3) / 4;       // 12500
    const int mlpGrid = (N_NODES + 63) / 64;     // 782

    // ---- Layer 0 (C_in = 128) ----
    gin_aggregate_bf<IN_C><<<aggGrid, 256, 0, stream>>>(xbf, rowptr, srcSorted, bufB);
    gin_mlp<IN_C, false><<<mlpGrid, 256, 0, stream>>>(bufB, wt[0], c_b1[0], wt[1], c_b2[0],
                                                      bufA, batch, sums, N_NODES);

    // ---- Layer 1 (C = 256) ----
    gin_aggregate_bf<HID><<<aggGrid, 256, 0, stream>>>(bufA, rowptr, srcSorted, bufB);
    gin_mlp<HID, false><<<mlpGrid, 256, 0, stream>>>(bufB, wt[2], c_b1[1], wt[3], c_b2[1],
                                                     bufA, batch, sums, N_NODES);

    // ---- Layer 2 (C = 256) with fused global mean-pool accumulation ----
    gin_aggregate_bf<HID><<<aggGrid, 256, 0, stream>>>(bufA, rowptr, srcSorted, bufB);
    gin_mlp<HID, true><<<mlpGrid, 256, 0, stream>>>(bufB, wt[4], c_b1[2], wt[5], c_b2[2],
                                                    bufA, batch, sums, N_NODES);

    // ---- Head MLP ----
    final_mlp_kernel<<<N_GRAPHS, 256, 0, stream>>>(sums, batch, out_w1, out_b1,
                                                   out_w2, out_b2, (float*)d_out);
}

// Round 13
// 479.088 us; speedup vs baseline: 1.0774x; 1.0774x over previous
//
#include <hip/hip_runtime.h>

#define N_NODES 50000
#define N_EDGES 800000
#define N_GRAPHS 512
#define IN_C 128
#define HID 256
#define OUT_C 16

typedef __attribute__((ext_vector_type(8))) short short8;
typedef __attribute__((ext_vector_type(4))) float f32x4;

__device__ __forceinline__ float bf2f(unsigned short u) {
    return __uint_as_float(((unsigned int)u) << 16);
}
__device__ __forceinline__ unsigned short f2bf(float f) {
    unsigned int u = __float_as_uint(f);
    u += 0x7fff + ((u >> 16) & 1);   // RNE
    return (unsigned short)(u >> 16);
}

// ===========================================================================
// Prep (single dispatch): x -> bf16, six weight transposes (K x 256 fp32 ->
// 256 x K bf16), zero deg, zero sums.
// ===========================================================================
struct PrepArgs {
    const float* x;
    const float* w[6];      // K x 256 row-major; K = 128 for w[0], else 256
    ushort* xbf;
    ushort* wt[6];
    int* deg;
    float* sums;
};

__global__ __launch_bounds__(256) void prep_kernel(PrepArgs a) {
    const int X4    = N_NODES * IN_C / 4;
    const int TW    = IN_C * HID;
    const int TH    = HID * HID;
    const int TBASE = X4;
    const int TEND  = TBASE + TW + 5 * TH;
    const int D4    = N_NODES / 4;
    const int DBASE = TEND;
    const int SBASE = DBASE + D4;
    const int S4    = N_GRAPHS * HID / 4;
    const long total = (long)SBASE + S4;

    long stride = (long)gridDim.x * blockDim.x;
    for (long i = (long)blockIdx.x * blockDim.x + threadIdx.x; i < total; i += stride) {
        if (i < X4) {
            float4 v = ((const float4*)a.x)[i];
            ushort4 o;
            o.x = f2bf(v.x); o.y = f2bf(v.y); o.z = f2bf(v.z); o.w = f2bf(v.w);
            ((ushort4*)a.xbf)[i] = o;
        } else if (i < TEND) {
            long r = i - TBASE;
            int wi, shift;
            long off;
            if (r < TW) { wi = 0; shift = 7; off = r; }
            else { r -= TW; wi = 1 + (int)(r / TH); shift = 8; off = r % TH; }
            int n = (int)(off >> shift);
            int k = (int)(off - ((long)n << shift));
            a.wt[wi][off] = f2bf(a.w[wi][(long)k * HID + n]);
        } else if (i < SBASE) {
            ((int4*)a.deg)[i - DBASE] = make_int4(0, 0, 0, 0);
        } else {
            ((float4*)a.sums)[i - SBASE] = make_float4(0.f, 0.f, 0.f, 0.f);
        }
    }
}

// ===========================================================================
// CSR build: deg histogram -> scan (2 fused dispatches) -> bucket by dst.
// ===========================================================================
__global__ void deg_kernel(const int* __restrict__ dst, int* __restrict__ deg) {
    int e = blockIdx.x * blockDim.x + threadIdx.x;
    if (e < N_EDGES) atomicAdd(&deg[dst[e]], 1);
}

__global__ __launch_bounds__(256) void scan_block(const int* __restrict__ deg,
                                                  int* __restrict__ partial,
                                                  int* __restrict__ blockSums) {
    __shared__ int s[256];
    int t = threadIdx.x;
    int i = blockIdx.x * 256 + t;
    int v = (i < N_NODES) ? deg[i] : 0;
    s[t] = v;
    __syncthreads();
    #pragma unroll
    for (int off = 1; off < 256; off <<= 1) {
        int add = (t >= off) ? s[t - off] : 0;
        __syncthreads();
        s[t] += add;
        __syncthreads();
    }
    if (i < N_NODES) partial[i] = s[t] - v;
    if (t == 255) blockSums[blockIdx.x] = s[255];
}

__global__ __launch_bounds__(256) void add_offsets_fused(
    const int* __restrict__ partial, const int* __restrict__ blockSums,
    int* __restrict__ rowptr, int* __restrict__ cursor, int nb) {
    __shared__ int s[256];
    __shared__ int myOff;
    int t = threadIdx.x;
    int v = (t < nb) ? blockSums[t] : 0;
    s[t] = v;
    __syncthreads();
    #pragma unroll
    for (int off = 1; off < 256; off <<= 1) {
        int add = (t >= off) ? s[t - off] : 0;
        __syncthreads();
        s[t] += add;
        __syncthreads();
    }
    if (t == blockIdx.x) myOff = s[t] - v;
    __syncthreads();
    int i = blockIdx.x * 256 + t;
    if (i < N_NODES) {
        int r = partial[i] + myOff;
        rowptr[i] = r;
        cursor[i] = r;
    }
    if (i == 0) rowptr[N_NODES] = N_EDGES;
}

__global__ void bucket_edges(const int* __restrict__ src, const int* __restrict__ dst,
                             int* __restrict__ cursor, int* __restrict__ srcSorted) {
    int e = blockIdx.x * blockDim.x + threadIdx.x;
    if (e >= N_EDGES) return;
    int p = atomicAdd(&cursor[dst[e]], 1);
    srcSorted[p] = src[e];
}

// ===========================================================================
// Aggregation (best measured config, VGPR 28): out[n] = h[n] + sum h[src].
// ===========================================================================
template <int C>
__global__ __launch_bounds__(256) void gin_aggregate_bf(const ushort* __restrict__ h,
                                                        const int* __restrict__ rowptr,
                                                        const int* __restrict__ srcIdx,
                                                        ushort* __restrict__ out) {
    constexpr int LPN = C / 8;
    constexpr int NPW = 64 / LPN;
    int wave = threadIdx.x >> 6;
    int lane = threadIdx.x & 63;
    int node = blockIdx.x * 4 + wave;
    if (node >= N_NODES) return;
    int sub = lane / LPN;
    int l = lane & (LPN - 1);
    int coff = l * 8;

    float acc[8];
    #pragma unroll
    for (int v = 0; v < 8; ++v) acc[v] = 0.f;

    if (sub == 0) {
        short8 sv = *(const short8*)(h + (long)node * C + coff);
        #pragma unroll
        for (int v = 0; v < 8; ++v) acc[v] += bf2f((unsigned short)sv[v]);
    }

    int beg = rowptr[node], end = rowptr[node + 1];
    int k = beg;
    for (; k + 4 * NPW <= end; k += 4 * NPW) {
        int si[4];
        #pragma unroll
        for (int u = 0; u < 4; ++u) si[u] = srcIdx[k + u * NPW + sub];
        short8 r[4];
        #pragma unroll
        for (int u = 0; u < 4; ++u) r[u] = *(const short8*)(h + (long)si[u] * C + coff);
        #pragma unroll
        for (int u = 0; u < 4; ++u)
            #pragma unroll
            for (int v = 0; v < 8; ++v) acc[v] += bf2f((unsigned short)r[u][v]);
    }
    for (; k < end; k += NPW) {
        int idx = k + sub;
        if (idx < end) {
            int sidx = srcIdx[idx];
            short8 r = *(const short8*)(h + (long)sidx * C + coff);
            #pragma unroll
            for (int v = 0; v < 8; ++v) acc[v] += bf2f((unsigned short)r[v]);
        }
    }

    #pragma unroll
    for (int v = 0; v < 8; ++v) {
        if constexpr (NPW == 4) acc[v] += __shfl_xor(acc[v], 16);
        acc[v] += __shfl_xor(acc[v], 32);
    }

    if (sub == 0) {
        short8 o;
        #pragma unroll
        for (int v = 0; v < 8; ++v) o[v] = (short)f2bf(acc[v]);
        *(short8*)(out + (long)node * C + coff) = o;
    }
}

// ===========================================================================
// Fused 2-layer MLP (R11 body — best measured): out = relu(relu(A@W1+b1)@W2+b2).
// __launch_bounds__(256, 4): 4 blocks/CU (16 waves/CU), LDS 32 KB.
// FUSE_POOL: epilogue accumulates into graph sums instead of writing out.
// ===========================================================================
template <int K1, bool FUSE_POOL>
__global__ __launch_bounds__(256, 4) void gin_mlp(
    const ushort* __restrict__ A,
    const ushort* __restrict__ w1t,
    const float* __restrict__ b1,
    const ushort* __restrict__ w2t,
    const float* __restrict__ b2,
    ushort* __restrict__ out,
    const int* __restrict__ batch,
    float* __restrict__ sums,
    int M)
{
    __shared__ short Ls[2048 * 8];      // 32 KB

    constexpr int NCH1 = K1 / 8;
    constexpr int NSLOT1 = 64 * NCH1;

    int t = threadIdx.x;
    int lane = t & 63;
    int wv = t >> 6;
    int quad = lane >> 4;
    int l15 = lane & 15;
    int swz = l15 & 7;
    int row0 = blockIdx.x * 64;
    int col0 = wv * 64;

    #pragma unroll
    for (int c = 0; c < NSLOT1; c += 256) {
        int s = c + t;
        int row = s / NCH1;
        int kcs = s & (NCH1 - 1);
        int kc = kcs ^ (row & 7);
        int grow = row0 + row;
        if (grow >= M) grow = M - 1;
        short8 v = *(const short8*)(A + (long)grow * K1 + kc * 8);
        *(short8*)&Ls[s * 8] = v;
    }
    __syncthreads();

    const f32x4 zero = {0.f, 0.f, 0.f, 0.f};
    f32x4 acc[4][4];

    #pragma unroll
    for (int i = 0; i < 4; ++i)
        #pragma unroll
        for (int j = 0; j < 4; ++j) acc[i][j] = zero;

    long brow[4];
    #pragma unroll
    for (int j = 0; j < 4; ++j)
        brow[j] = (long)(col0 + j * 16 + l15) * K1;

    #pragma unroll
    for (int s = 0; s < K1 / 32; ++s) {
        short8 a[4], b[4];
        #pragma unroll
        for (int i = 0; i < 4; ++i) {
            int row = i * 16 + l15;
            int slot = row * NCH1 + ((s * 4 + quad) ^ swz);
            a[i] = *(const short8*)&Ls[slot * 8];
        }
        #pragma unroll
        for (int j = 0; j < 4; ++j)
            b[j] = *(const short8*)(w1t + brow[j] + s * 32 + quad * 8);
        #pragma unroll
        for (int i = 0; i < 4; ++i)
            #pragma unroll
            for (int j = 0; j < 4; ++j)
                acc[i][j] = __builtin_amdgcn_mfma_f32_16x16x32_bf16(a[i], b[j], acc[i][j], 0, 0, 0);
    }
    __syncthreads();

    {
        float bv[4];
        #pragma unroll
        for (int j = 0; j < 4; ++j) bv[j] = b1[col0 + j * 16 + l15];
        #pragma unroll
        for (int i = 0; i < 4; ++i)
            #pragma unroll
            for (int j = 0; j < 4; ++j) {
                int col = col0 + j * 16 + l15;
                int kc2 = col >> 3, sub = col & 7;
                #pragma unroll
                for (int r = 0; r < 4; ++r) {
                    int row = i * 16 + quad * 4 + r;
                    int slot = row * 32 + (kc2 ^ (row & 7));
                    float o = fmaxf(acc[i][j][r] + bv[j], 0.f);
                    Ls[slot * 8 + sub] = (short)f2bf(o);
                }
            }
    }
    __syncthreads();

    #pragma unroll
    for (int i = 0; i < 4; ++i)
        #pragma unroll
        for (int j = 0; j < 4; ++j) acc[i][j] = zero;

    long brow2[4];
    #pragma unroll
    for (int j = 0; j < 4; ++j)
        brow2[j] = (long)(col0 + j * 16 + l15) * 256;

    #pragma unroll
    for (int s = 0; s < 8; ++s) {
        short8 a[4], b[4];
        #pragma unroll
        for (int i = 0; i < 4; ++i) {
            int row = i * 16 + l15;
            int slot = row * 32 + ((s * 4 + quad) ^ swz);
            a[i] = *(const short8*)&Ls[slot * 8];
        }
        #pragma unroll
        for (int j = 0; j < 4; ++j)
            b[j] = *(const short8*)(w2t + brow2[j] + s * 32 + quad * 8);
        #pragma unroll
        for (int i = 0; i < 4; ++i)
            #pragma unroll
            for (int j = 0; j < 4; ++j)
                acc[i][j] = __builtin_amdgcn_mfma_f32_16x16x32_bf16(a[i], b[j], acc[i][j], 0, 0, 0);
    }

    float bv[4];
    #pragma unroll
    for (int j = 0; j < 4; ++j) bv[j] = b2[col0 + j * 16 + l15];

    if constexpr (!FUSE_POOL) {
        #pragma unroll
        for (int i = 0; i < 4; ++i)
            #pragma unroll
            for (int r = 0; r < 4; ++r) {
                int row = row0 + i * 16 + quad * 4 + r;
                if (row >= M) continue;
                #pragma unroll
                for (int j = 0; j < 4; ++j) {
                    float o = fmaxf(acc[i][j][r] + bv[j], 0.f);
                    out[(long)row * 256 + col0 + j * 16 + l15] = f2bf(o);
                }
            }
    } else {
        float pacc[4];
        #pragma unroll
        for (int j = 0; j < 4; ++j) pacc[j] = 0.f;
        int cur = -1;
        #pragma unroll
        for (int i = 0; i < 4; ++i) {
            #pragma unroll
            for (int r = 0; r < 4; ++r) {
                int row = row0 + i * 16 + quad * 4 + r;
                if (row >= M) continue;
                int g = batch[row];
                if (g != cur) {
                    if (cur >= 0) {
                        #pragma unroll
                        for (int j = 0; j < 4; ++j)
                            atomicAdd(&sums[(long)cur * 256 + col0 + j * 16 + l15], pacc[j]);
                    }
                    cur = g;
                    #pragma unroll
                    for (int j = 0; j < 4; ++j) pacc[j] = 0.f;
                }
                #pragma unroll
                for (int j = 0; j < 4; ++j)
                    pacc[j] += fmaxf(acc[i][j][r] + bv[j], 0.f);
            }
        }
        if (cur >= 0) {
            #pragma unroll
            for (int j = 0; j < 4; ++j)
                atomicAdd(&sums[(long)cur * 256 + col0 + j * 16 + l15], pacc[j]);
        }
    }
}

// ===========================================================================
// Head MLP (fp32): one block per graph; count via binary search on batch.
// ===========================================================================
__global__ __launch_bounds__(256) void final_mlp_kernel(
    const float* __restrict__ sums, const int* __restrict__ batch,
    const float* __restrict__ w1, const float* __restrict__ b1,
    const float* __restrict__ w2, const float* __restrict__ b2,
    float* __restrict__ out) {
    __shared__ float row[HID];
    __shared__ float hid[HID];
    __shared__ int cntS;
    int g = blockIdx.x;
    int t = threadIdx.x;
    if (t == 0) {
        int lo = 0, hi = N_NODES;
        while (lo < hi) { int m = (lo + hi) >> 1; if (batch[m] < g) lo = m + 1; else hi = m; }
        int lo2 = lo, hi2 = N_NODES;
        while (lo2 < hi2) { int m = (lo2 + hi2) >> 1; if (batch[m] < g + 1) lo2 = m + 1; else hi2 = m; }
        cntS = lo2 - lo;
    }
    __syncthreads();
    float cnt = fmaxf((float)cntS, 1.0f);
    row[t] = sums[(long)g * HID + t] / cnt;
    __syncthreads();
    float acc = b1[t];
    for (int k = 0; k < HID; ++k) acc += row[k] * w1[k * HID + t];
    hid[t] = fmaxf(acc, 0.f);
    __syncthreads();
    if (t < OUT_C) {
        float o = b2[t];
        for (int k = 0; k < HID; ++k) o += hid[k] * w2[k * OUT_C + t];
        out[(long)g * OUT_C + t] = o;
    }
}

// ---------------------------------------------------------------------------
extern "C" void kernel_launch(void* const* d_in, const int* in_sizes, int n_in,
                              void* d_out, int out_size, void* d_ws, size_t ws_size,
                              hipStream_t stream) {
    const float* x     = (const float*)d_in[0];
    const int*   ei    = (const int*)d_in[1];
    const int*   batch = (const int*)d_in[2];
    const int*   src   = ei;
    const int*   dst   = ei + N_EDGES;

    const float* c_w1[3] = { (const float*)d_in[3],  (const float*)d_in[7],  (const float*)d_in[11] };
    const float* c_b1[3] = { (const float*)d_in[4],  (const float*)d_in[8],  (const float*)d_in[12] };
    const float* c_w2[3] = { (const float*)d_in[5],  (const float*)d_in[9],  (const float*)d_in[13] };
    const float* c_b2[3] = { (const float*)d_in[6],  (const float*)d_in[10], (const float*)d_in[14] };
    const float* out_w1 = (const float*)d_in[15];
    const float* out_b1 = (const float*)d_in[16];
    const float* out_w2 = (const float*)d_in[17];
    const float* out_b2 = (const float*)d_in[18];

    // ---- Workspace layout (16B aligned) ----
    char* p = (char*)d_ws;
    auto alloc = [&](size_t bytes) {
        char* r = p;
        p += (bytes + 15) & ~(size_t)15;
        return r;
    };
    ushort* xbf  = (ushort*)alloc((size_t)N_NODES * IN_C * 2);
    ushort* bufA = (ushort*)alloc((size_t)N_NODES * HID * 2);
    ushort* bufB = (ushort*)alloc((size_t)N_NODES * HID * 2);
    ushort* wt[6];
    wt[0] = (ushort*)alloc((size_t)IN_C * HID * 2);
    for (int i = 1; i < 6; ++i) wt[i] = (ushort*)alloc((size_t)HID * HID * 2);
    float* sums   = (float*)alloc((size_t)N_GRAPHS * HID * 4);
    int* deg       = (int*)alloc((size_t)N_NODES * 4);
    int* rowptr    = (int*)alloc((size_t)(N_NODES + 1) * 4);
    int* blockSums = (int*)alloc(256 * 4);
    int* cursor    = (int*)alloc((size_t)N_NODES * 4);
    int* srcSorted = (int*)alloc((size_t)N_EDGES * 4);

    const int nb = (N_NODES + 255) / 256;

    // ---- Prep: one dispatch for casts + transposes + zeroing ----
    {
        PrepArgs a;
        a.x = x;
        a.w[0] = c_w1[0]; a.w[1] = c_w2[0];
        a.w[2] = c_w1[1]; a.w[3] = c_w2[1];
        a.w[4] = c_w1[2]; a.w[5] = c_w2[2];
        a.xbf = xbf;
        for (int i = 0; i < 6; ++i) a.wt[i] = wt[i];
        a.deg = deg;
        a.sums = sums;
        prep_kernel<<<2048, 256, 0, stream>>>(a);
    }

    // ---- Build CSR by dst ----
    deg_kernel<<<(N_EDGES + 255) / 256, 256, 0, stream>>>(dst, deg);
    scan_block<<<nb, 256, 0, stream>>>(deg, rowptr, blockSums);
    add_offsets_fused<<<nb, 256, 0, stream>>>(rowptr, blockSums, rowptr, cursor, nb);
    bucket_edges<<<(N_EDGES + 255) / 256, 256, 0, stream>>>(src, dst, cursor, srcSorted);

    const int aggGrid = (N_NODES + 3) / 4;       // 12500
    const int mlpGrid = (N_NODES + 63) / 64;     // 782

    // ---- Layer 0 (C_in = 128) ----
    gin_aggregate_bf<IN_C><<<aggGrid, 256, 0, stream>>>(xbf, rowptr, srcSorted, bufB);
    gin_mlp<IN_C, false><<<mlpGrid, 256, 0, stream>>>(bufB, wt[0], c_b1[0], wt[1], c_b2[0],
                                                      bufA, batch, sums, N_NODES);

    // ---- Layer 1 (C = 256) ----
    gin_aggregate_bf<HID><<<aggGrid, 256, 0, stream>>>(bufA, rowptr, srcSorted, bufB);
    gin_mlp<HID, false><<<mlpGrid, 256, 0, stream>>>(bufB, wt[2], c_b1[1], wt[3], c_b2[1],
                                                     bufA, batch, sums, N_NODES);

    // ---- Layer 2 (C = 256) with fused global mean-pool accumulation ----
    gin_aggregate_bf<HID><<<aggGrid, 256, 0, stream>>>(bufA, rowptr, srcSorted, bufB);
    gin_mlp<HID, true><<<mlpGrid, 256, 0, stream>>>(bufB, wt[4], c_b1[2], wt[5], c_b2[2],
                                                    bufA, batch, sums, N_NODES);

    // ---- Head MLP ----
    final_mlp_kernel<<<N_GRAPHS, 256, 0, stream>>>(sums, batch, out_w1, out_b1,
                                                   out_w2, out_b2, (float*)d_out);
}